// Round 1
// baseline (280.481 us; speedup 1.0000x reference)
//
#include <hip/hip_runtime.h>
#include <hip/hip_bf16.h>

#define Bb 8
#define Tt 4096
#define Dd 1024
#define Hh 1024
#define Mm (Bb * Tt)
#define NCHUNK 32
#define CLEN 128

typedef float f32x4 __attribute__((ext_vector_type(4)));
typedef short bf16x8 __attribute__((ext_vector_type(8)));

__device__ __forceinline__ unsigned f2bfu(float x) {
  unsigned u = __float_as_uint(x);
  return (u + 0x7fffu + ((u >> 16) & 1u)) >> 16;  // RNE to bf16 bits
}
__device__ __forceinline__ float bflo(unsigned u) { return __uint_as_float(u << 16); }
__device__ __forceinline__ float bfhi(unsigned u) { return __uint_as_float(u & 0xffff0000u); }

// ---------------- fp32 -> bf16 conversion (4 elems/thread/iter) ----------------
__global__ void cvt_kernel(const float* __restrict__ src, unsigned short* __restrict__ dst,
                           int n4) {
  int i = blockIdx.x * blockDim.x + threadIdx.x;
  int stride = gridDim.x * blockDim.x;
  for (; i < n4; i += stride) {
    float4 v = reinterpret_cast<const float4*>(src)[i];
    ushort4 o;
    o.x = (unsigned short)f2bfu(v.x);
    o.y = (unsigned short)f2bfu(v.y);
    o.z = (unsigned short)f2bfu(v.z);
    o.w = (unsigned short)f2bfu(v.w);
    reinterpret_cast<ushort4*>(dst)[i] = o;
  }
}

// ---------------- async global->LDS, 16B per lane ----------------
__device__ __forceinline__ void async16(const unsigned short* g, unsigned short* l) {
  __builtin_amdgcn_global_load_lds(
      (const __attribute__((address_space(1))) unsigned int*)g,
      (__attribute__((address_space(3))) unsigned int*)l, 16, 0, 0);
}

// ---------------- GEMM: k = x*Wz^T+bz, pre = x*Wh^T+bh, fused gate epilogue ----
// Block: 256 thr (4 waves). Tile: BM=128 rows of x, 64 h-columns.
// B-tile rows 0..63 = Wz[h0..h0+63], rows 64..127 = Wh[h0..h0+63]. BK=64.
// LDS linear (global_load_lds), bank spread via 16B-slot XOR swizzle applied to
// BOTH the global source slot and the ds_read address (same involution).
__global__ void __launch_bounds__(256, 2) gemm_kernel(
    const unsigned short* __restrict__ xb,
    const unsigned short* __restrict__ wzb,
    const unsigned short* __restrict__ whb,
    const float* __restrict__ bz,
    const float* __restrict__ bh,
    unsigned int* __restrict__ P) {
  __shared__ unsigned short As[128 * 64];
  __shared__ unsigned short Bs[128 * 64];
  const int m0 = blockIdx.x * 128;
  const int h0 = blockIdx.y * 64;
  const int t = threadIdx.x;
  const int w = t >> 6;       // wave 0..3 -> m rows [32w, 32w+32)
  const int l = t & 63;
  const int ln = l & 15;
  const int l4 = l >> 4;

  f32x4 acc[2][8];
#pragma unroll
  for (int mf = 0; mf < 2; ++mf)
#pragma unroll
    for (int nf = 0; nf < 8; ++nf)
      acc[mf][nf] = f32x4{0.f, 0.f, 0.f, 0.f};

  for (int kt = 0; kt < Dd / 64; ++kt) {
    const int k0 = kt * 64;
    // stage A tile: 128x64 bf16, 16KB = 4 x (256 lanes x 16B)
#pragma unroll
    for (int i = 0; i < 4; ++i) {
      const int blk = i * 256 + t;              // 16B-block id (linear in LDS)
      const int r = blk >> 3;                   // row, 8 slots of 16B per row
      const int slot = (blk & 7) ^ (r & 7);     // pre-swizzled global slot
      async16(xb + (size_t)(m0 + r) * Dd + (k0 + slot * 8), &As[blk * 8]);
    }
    // stage B tile: rows 0-63 Wz, 64-127 Wh (branch uniform per i)
#pragma unroll
    for (int i = 0; i < 4; ++i) {
      const int blk = i * 256 + t;
      const int r = blk >> 3;
      const int slot = (blk & 7) ^ (r & 7);
      const unsigned short* src =
          (r < 64) ? (wzb + (size_t)(h0 + r) * Dd + (k0 + slot * 8))
                   : (whb + (size_t)(h0 + r - 64) * Dd + (k0 + slot * 8));
      async16(src, &Bs[blk * 8]);
    }
    __syncthreads();  // compiler emits vmcnt(0) drain before barrier

#pragma unroll
    for (int kk = 0; kk < 2; ++kk) {
      bf16x8 af[2];
#pragma unroll
      for (int mf = 0; mf < 2; ++mf) {
        const int row = w * 32 + mf * 16 + ln;
        const int kb = (kk * 64 + l4 * 16) ^ ((row & 7) << 4);
        af[mf] = *reinterpret_cast<const bf16x8*>(
            reinterpret_cast<const char*>(As) + row * 128 + kb);
      }
#pragma unroll
      for (int nf = 0; nf < 8; ++nf) {
        const int row = nf * 16 + ln;
        const int kb = (kk * 64 + l4 * 16) ^ ((row & 7) << 4);
        bf16x8 bfr = *reinterpret_cast<const bf16x8*>(
            reinterpret_cast<const char*>(Bs) + row * 128 + kb);
#pragma unroll
        for (int mf = 0; mf < 2; ++mf)
          acc[mf][nf] =
              __builtin_amdgcn_mfma_f32_16x16x32_bf16(af[mf], bfr, acc[mf][nf], 0, 0, 0);
      }
    }
    __syncthreads();
  }

  // Epilogue: C/D layout col = lane&15, row = (lane>>4)*4 + q  [m89-verified]
  // nf in [0,4) = k-columns (Wz), nf+4 = pre-columns (Wh), same h per thread.
#pragma unroll
  for (int mf = 0; mf < 2; ++mf) {
#pragma unroll
    for (int nf = 0; nf < 4; ++nf) {
      const int hcol = h0 + nf * 16 + ln;
      const float bzv = bz[hcol];
      const float bhv = bh[hcol];
#pragma unroll
      for (int q = 0; q < 4; ++q) {
        const int m = m0 + w * 32 + mf * 16 + l4 * 4 + q;
        const float kv = acc[mf][nf][q] + bzv;
        const float pv = acc[mf][nf + 4][q] + bhv;
        const float ek = __expf(kv);
        const float a = 1.f / (1.f + ek);   // 1 - sigmoid(k) = coeff
        const float z = 1.f - a;            // sigmoid(k)
        const float g = (pv >= 0.f) ? (pv + 0.5f) : (1.f / (1.f + __expf(-pv)));
        const float c = z * g;
        P[(size_t)m * Hh + hcol] = f2bfu(a) | (f2bfu(c) << 16);
      }
    }
  }
}

// ---------------- scan pass 1: per-chunk affine reduction (A, Q) ----------------
__global__ void scan_pass1(const unsigned int* __restrict__ P,
                           float* __restrict__ Pp, float* __restrict__ Qq) {
  const int h = blockIdx.x * 256 + threadIdx.x;
  const int ch = blockIdx.y;
  const int b = blockIdx.z;
  const unsigned int* p = P + ((size_t)(b * Tt + ch * CLEN)) * Hh + h;
  float A = 1.f, Q = 0.f;
#pragma unroll 8
  for (int i = 0; i < CLEN; ++i) {
    const unsigned u = p[(size_t)i * Hh];
    Q = fmaf(bflo(u), Q, bfhi(u));
    A *= bflo(u);
  }
  const int idx = ch * (Bb * Hh) + b * Hh + h;
  Pp[idx] = A;
  Qq[idx] = Q;
}

// ---------------- scan pass 2: sequential chunk combine (tiny) ----------------
__global__ void scan_pass2(const float* __restrict__ h0raw,
                           const float* __restrict__ Pp, const float* __restrict__ Qq,
                           float* __restrict__ Hinit) {
  const int bh = blockIdx.x * 256 + threadIdx.x;  // 0..8191
  const float x = h0raw[bh];
  float hs = (x >= 0.f) ? (x + 0.5f) : (1.f / (1.f + __expf(-x)));  // g(h_0)
  for (int ch = 0; ch < NCHUNK; ++ch) {
    const int idx = ch * (Bb * Hh) + bh;
    Hinit[idx] = hs;
    hs = fmaf(Pp[idx], hs, Qq[idx]);
  }
}

// ---------------- scan pass 3: in-chunk scan, write outputs ----------------
__global__ void scan_pass3(const unsigned int* __restrict__ P,
                           const float* __restrict__ Hinit,
                           float* __restrict__ out) {
  const int h = blockIdx.x * 256 + threadIdx.x;
  const int ch = blockIdx.y;
  const int b = blockIdx.z;
  float hs = Hinit[ch * (Bb * Hh) + b * Hh + h];
  const size_t base = ((size_t)(b * Tt + ch * CLEN)) * Hh + h;
  const unsigned int* p = P + base;
  float* o = out + base;
#pragma unroll 8
  for (int i = 0; i < CLEN; ++i) {
    const unsigned u = p[(size_t)i * Hh];
    hs = fmaf(bflo(u), hs, bfhi(u));
    o[(size_t)i * Hh] = hs;
  }
}

extern "C" void kernel_launch(void* const* d_in, const int* in_sizes, int n_in,
                              void* d_out, int out_size, void* d_ws, size_t ws_size,
                              hipStream_t stream) {
  const float* x  = (const float*)d_in[0];
  const float* h0 = (const float*)d_in[1];
  const float* Wz = (const float*)d_in[2];
  const float* bz = (const float*)d_in[3];
  const float* Wh = (const float*)d_in[4];
  const float* bh = (const float*)d_in[5];
  float* out = (float*)d_out;

  char* ws = (char*)d_ws;
  unsigned short* xb  = (unsigned short*)(ws);                       // 64 MiB
  unsigned short* wzb = (unsigned short*)(ws + 67108864);            // 2 MiB
  unsigned short* whb = (unsigned short*)(ws + 69206016);            // 2 MiB
  unsigned int*   P   = (unsigned int*)(ws + 71303168);              // 128 MiB
  float* Pp    = (float*)(ws + 205520896);                           // 1 MiB
  float* Qq    = (float*)(ws + 206569472);                           // 1 MiB
  float* Hinit = (float*)(ws + 207618048);                           // 1 MiB

  cvt_kernel<<<4096, 256, 0, stream>>>(x, xb, Mm * Dd / 4);
  cvt_kernel<<<1024, 256, 0, stream>>>(Wz, wzb, Hh * Dd / 4);
  cvt_kernel<<<1024, 256, 0, stream>>>(Wh, whb, Hh * Dd / 4);

  dim3 ggrid(Mm / 128, Hh / 64);
  gemm_kernel<<<ggrid, 256, 0, stream>>>(xb, wzb, whb, bz, bh, P);

  dim3 sgrid(Hh / 256, NCHUNK, Bb);
  scan_pass1<<<sgrid, 256, 0, stream>>>(P, Pp, Qq);
  scan_pass2<<<Bb * Hh / 256, 256, 0, stream>>>(h0, Pp, Qq, Hinit);
  scan_pass3<<<sgrid, 256, 0, stream>>>(P, Hinit, out);
}

// Round 2
// 272.988 us; speedup vs baseline: 1.0274x; 1.0274x over previous
//
#include <hip/hip_runtime.h>
#include <hip/hip_bf16.h>

#define Bb 8
#define Tt 4096
#define Dd 1024
#define Hh 1024
#define Mm (Bb * Tt)
#define NCHUNK 32
#define CLEN 128

typedef float f32x4 __attribute__((ext_vector_type(4)));
typedef short bf16x8 __attribute__((ext_vector_type(8)));

__device__ __forceinline__ unsigned f2bfu(float x) {
  unsigned u = __float_as_uint(x);
  return (u + 0x7fffu + ((u >> 16) & 1u)) >> 16;  // RNE to bf16 bits
}
__device__ __forceinline__ float bflo(unsigned u) { return __uint_as_float(u << 16); }
__device__ __forceinline__ float bfhi(unsigned u) { return __uint_as_float(u & 0xffff0000u); }

// ---------------- fp32 -> bf16 conversion ----------------
__global__ void cvt_kernel(const float* __restrict__ src, unsigned short* __restrict__ dst,
                           int n4) {
  int i = blockIdx.x * blockDim.x + threadIdx.x;
  int stride = gridDim.x * blockDim.x;
  for (; i < n4; i += stride) {
    float4 v = reinterpret_cast<const float4*>(src)[i];
    ushort4 o;
    o.x = (unsigned short)f2bfu(v.x);
    o.y = (unsigned short)f2bfu(v.y);
    o.z = (unsigned short)f2bfu(v.z);
    o.w = (unsigned short)f2bfu(v.w);
    reinterpret_cast<ushort4*>(dst)[i] = o;
  }
}

__device__ __forceinline__ void async16(const unsigned short* g, unsigned short* l) {
  __builtin_amdgcn_global_load_lds(
      (const __attribute__((address_space(1))) unsigned int*)g,
      (__attribute__((address_space(3))) unsigned int*)l, 16, 0, 0);
}

// =====================================================================
// 256x256-tile 8-phase GEMM. BK=64 split into 2 K-halves of 32 cols.
// LDS: A,B each 2 slots x 2 khalves x (256 rows x 32 cols bf16 = 16KiB).
// 8 waves (2M x 4N), per-wave C = 128 x 64. K=1024 -> 16 K-tiles, 2/iter.
// Every half-tile staged exactly 6 phases before first use; vmcnt(6) at
// even phases guarantees it. Raw s_barrier (no vmcnt drain) throughout.
// B cols (N=2048 stacked): 16-col groups alternate Wz / Wh for same h,
// so each thread's acc holds (k, pre) pairs for identical (m,h).
// LDS swizzle: slot' = (l4 + (row>>1)) & 3  -> 8 lanes per bank-quad
// (even) on ds_read_b128; source pre-swizzled so lane l4 gets k-chunk l4.
// =====================================================================
template <int MF0>
__device__ __forceinline__ void mfma16(const bf16x8 af[4], const bf16x8 bfr[4],
                                       f32x4 (&acc)[8][4]) {
#pragma unroll
  for (int i = 0; i < 4; ++i)
#pragma unroll
    for (int j = 0; j < 4; ++j)
      acc[MF0 + i][j] =
          __builtin_amdgcn_mfma_f32_16x16x32_bf16(af[i], bfr[j], acc[MF0 + i][j], 0, 0, 0);
}

__device__ __forceinline__ void phase_pre(bool guard) {
  if (guard) asm volatile("s_waitcnt vmcnt(6)" ::: "memory");
  __builtin_amdgcn_sched_barrier(0);
  __builtin_amdgcn_s_barrier();
}
__device__ __forceinline__ void phase_post() {
  __builtin_amdgcn_sched_barrier(0);
  __builtin_amdgcn_s_barrier();
}

__global__ void __launch_bounds__(512, 1) gemm_kernel(
    const unsigned short* __restrict__ xb,
    const unsigned short* __restrict__ wzb,
    const unsigned short* __restrict__ whb,
    const float* __restrict__ bz,
    const float* __restrict__ bh,
    unsigned int* __restrict__ P) {
  __shared__ unsigned short lds[65536];  // 128 KiB: A [0,32768), B [32768,65536)
  const int tid = threadIdx.x;
  const int wid = tid >> 6;
  const int wm = wid >> 2;      // 0..1
  const int wn = wid & 3;       // 0..3
  const int l = tid & 63, ln = l & 15, l4 = l >> 4;

  // bijective XCD swizzle (nwg=1024, divisible by 8)
  const int id = blockIdx.x;
  const int sw = (id & 7) * 128 + (id >> 3);
  const int mb = sw >> 3, nb = sw & 7;
  const int m0 = mb * 256, h0 = nb * 128;

  // staging helpers (each = 2 global_load_lds per thread = one 16KiB half-tile)
  auto stage_a = [&](int kt, int kh) {
    unsigned short* dst = &lds[((kt & 1) * 2 + kh) * 8192];
#pragma unroll
    for (int c = 0; c < 2; ++c) {
      const int blk = c * 512 + tid;
      const int r = blk >> 2, sl = blk & 3;
      const int chunk = (sl - (r >> 1)) & 3;
      async16(xb + (size_t)(m0 + r) * Dd + (kt * 64 + kh * 32 + chunk * 8), dst + blk * 8);
    }
  };
  auto stage_b = [&](int kt, int kh) {
    unsigned short* dst = &lds[32768 + ((kt & 1) * 2 + kh) * 8192];
#pragma unroll
    for (int c = 0; c < 2; ++c) {
      const int blk = c * 512 + tid;
      const int r = blk >> 2, sl = blk & 3;
      const int chunk = (sl - (r >> 1)) & 3;
      const int sub16 = r >> 4;                       // 0..15; even=Wz, odd=Wh
      const int hrow = h0 + ((sub16 >> 1) << 4) + (r & 15);
      const unsigned short* src = (sub16 & 1) ? whb : wzb;
      async16(src + (size_t)hrow * Dd + (kt * 64 + kh * 32 + chunk * 8), dst + blk * 8);
    }
  };

  // precomputed fragment offsets (shorts) within a 16KiB half-region
  int oA[8], oB[4];
#pragma unroll
  for (int mf = 0; mf < 8; ++mf) {
    const int row = wm * 128 + mf * 16 + ln;
    const int sl = (l4 + (row >> 1)) & 3;
    oA[mf] = row * 32 + sl * 8;
  }
#pragma unroll
  for (int nf = 0; nf < 4; ++nf) {
    const int row = wn * 64 + nf * 16 + ln;
    const int sl = (l4 + (row >> 1)) & 3;
    oB[nf] = row * 32 + sl * 8;
  }

  f32x4 acc[8][4];
#pragma unroll
  for (int i = 0; i < 8; ++i)
#pragma unroll
    for (int j = 0; j < 4; ++j) acc[i][j] = f32x4{0.f, 0.f, 0.f, 0.f};

  // prologue: stage (t0,k0) (t0,k1) (t1,k0) = 12 ops; first 4 = (t0,k0) A+B
  stage_a(0, 0); stage_b(0, 0);
  stage_a(0, 1); stage_b(0, 1);
  stage_a(1, 0); stage_b(1, 0);
  asm volatile("s_waitcnt vmcnt(8)" ::: "memory");
  __builtin_amdgcn_sched_barrier(0);
  __builtin_amdgcn_s_barrier();

  for (int it = 0; it < 8; ++it) {
    const int t1 = 2 * it + 1;
    const int t2 = (2 * it + 2) & 15;  // wraps on last iter (redundant stage, drained)
    const int t3 = (2 * it + 3) & 15;
    bf16x8 bfr[4];

#define DS_B(SLOT, KH)                                                        \
  {                                                                           \
    const unsigned short* base_ = &lds[32768 + ((SLOT)*2 + (KH)) * 8192];     \
    bfr[0] = *(const bf16x8*)(base_ + oB[0]);                                 \
    bfr[1] = *(const bf16x8*)(base_ + oB[1]);                                 \
    bfr[2] = *(const bf16x8*)(base_ + oB[2]);                                 \
    bfr[3] = *(const bf16x8*)(base_ + oB[3]);                                 \
  }
#define DS_A(SLOT, KH, MF0)                                                   \
  {                                                                           \
    const unsigned short* base_ = &lds[((SLOT)*2 + (KH)) * 8192];             \
    af[0] = *(const bf16x8*)(base_ + oA[(MF0) + 0]);                          \
    af[1] = *(const bf16x8*)(base_ + oA[(MF0) + 1]);                          \
    af[2] = *(const bf16x8*)(base_ + oA[(MF0) + 2]);                          \
    af[3] = *(const bf16x8*)(base_ + oA[(MF0) + 3]);                          \
  }

    {  // ph1: compute (slot0,kh0) mf0-3; stage A(t1,kh1)
      bf16x8 af[4];
      DS_B(0, 0); DS_A(0, 0, 0);
      stage_a(t1, 1);
      phase_pre(false);
      __builtin_amdgcn_s_setprio(1); mfma16<0>(af, bfr, acc); __builtin_amdgcn_s_setprio(0);
      phase_post();
    }
    {  // ph2: compute (slot0,kh0) mf4-7; stage B(t1,kh1); guard
      bf16x8 af[4];
      DS_A(0, 0, 4);
      stage_b(t1, 1);
      phase_pre(true);
      __builtin_amdgcn_s_setprio(1); mfma16<4>(af, bfr, acc); __builtin_amdgcn_s_setprio(0);
      phase_post();
    }
    {  // ph3: compute (slot0,kh1) mf0-3; stage A(t2,kh0)
      bf16x8 af[4];
      DS_B(0, 1); DS_A(0, 1, 0);
      stage_a(t2, 0);
      phase_pre(false);
      __builtin_amdgcn_s_setprio(1); mfma16<0>(af, bfr, acc); __builtin_amdgcn_s_setprio(0);
      phase_post();
    }
    {  // ph4: compute (slot0,kh1) mf4-7; stage B(t2,kh0); guard
      bf16x8 af[4];
      DS_A(0, 1, 4);
      stage_b(t2, 0);
      phase_pre(true);
      __builtin_amdgcn_s_setprio(1); mfma16<4>(af, bfr, acc); __builtin_amdgcn_s_setprio(0);
      phase_post();
    }
    {  // ph5: compute (slot1,kh0) mf0-3; stage A(t2,kh1)
      bf16x8 af[4];
      DS_B(1, 0); DS_A(1, 0, 0);
      stage_a(t2, 1);
      phase_pre(false);
      __builtin_amdgcn_s_setprio(1); mfma16<0>(af, bfr, acc); __builtin_amdgcn_s_setprio(0);
      phase_post();
    }
    {  // ph6: compute (slot1,kh0) mf4-7; stage B(t2,kh1); guard
      bf16x8 af[4];
      DS_A(1, 0, 4);
      stage_b(t2, 1);
      phase_pre(true);
      __builtin_amdgcn_s_setprio(1); mfma16<4>(af, bfr, acc); __builtin_amdgcn_s_setprio(0);
      phase_post();
    }
    {  // ph7: compute (slot1,kh1) mf0-3; stage A(t3,kh0)
      bf16x8 af[4];
      DS_B(1, 1); DS_A(1, 1, 0);
      stage_a(t3, 0);
      phase_pre(false);
      __builtin_amdgcn_s_setprio(1); mfma16<0>(af, bfr, acc); __builtin_amdgcn_s_setprio(0);
      phase_post();
    }
    {  // ph8: compute (slot1,kh1) mf4-7; stage B(t3,kh0); guard
      bf16x8 af[4];
      DS_A(1, 1, 4);
      stage_b(t3, 0);
      phase_pre(true);
      __builtin_amdgcn_s_setprio(1); mfma16<4>(af, bfr, acc); __builtin_amdgcn_s_setprio(0);
      phase_post();
    }
#undef DS_A
#undef DS_B
  }

  // drain pending LDS-DMA before block can retire (LDS gets reallocated)
  asm volatile("s_waitcnt vmcnt(0)" ::: "memory");

  // Epilogue: C/D layout col=lane&15, row=(lane>>4)*4+q.
  // nf = 2p   -> k  (Wz cols),  nf = 2p+1 -> pre (Wh cols), h identical.
#pragma unroll
  for (int p = 0; p < 2; ++p) {
    const int hcol = h0 + (wn * 2 + p) * 16 + ln;
    const float bzv = bz[hcol];
    const float bhv = bh[hcol];
#pragma unroll
    for (int mf = 0; mf < 8; ++mf) {
#pragma unroll
      for (int q = 0; q < 4; ++q) {
        const int m = m0 + wm * 128 + mf * 16 + l4 * 4 + q;
        const float kv = acc[mf][2 * p][q] + bzv;
        const float pv = acc[mf][2 * p + 1][q] + bhv;
        const float ek = __expf(kv);
        const float a = 1.f / (1.f + ek);   // 1 - sigmoid(k)
        const float z = 1.f - a;            // sigmoid(k)
        const float g = (pv >= 0.f) ? (pv + 0.5f) : (1.f / (1.f + __expf(-pv)));
        const float c = z * g;
        P[(size_t)m * Hh + hcol] = f2bfu(a) | (f2bfu(c) << 16);
      }
    }
  }
}

// ---------------- scan pass 1: per-chunk affine reduction (A, Q) ----------------
__global__ void scan_pass1(const unsigned int* __restrict__ P,
                           float* __restrict__ Pp, float* __restrict__ Qq) {
  const int h = blockIdx.x * 256 + threadIdx.x;
  const int ch = blockIdx.y;
  const int b = blockIdx.z;
  const unsigned int* p = P + ((size_t)(b * Tt + ch * CLEN)) * Hh + h;
  float A = 1.f, Q = 0.f;
#pragma unroll 8
  for (int i = 0; i < CLEN; ++i) {
    const unsigned u = p[(size_t)i * Hh];
    Q = fmaf(bflo(u), Q, bfhi(u));
    A *= bflo(u);
  }
  const int idx = ch * (Bb * Hh) + b * Hh + h;
  Pp[idx] = A;
  Qq[idx] = Q;
}

// ---------------- scan pass 2: sequential chunk combine (tiny) ----------------
__global__ void scan_pass2(const float* __restrict__ h0raw,
                           const float* __restrict__ Pp, const float* __restrict__ Qq,
                           float* __restrict__ Hinit) {
  const int bh = blockIdx.x * 256 + threadIdx.x;  // 0..8191
  const float x = h0raw[bh];
  float hs = (x >= 0.f) ? (x + 0.5f) : (1.f / (1.f + __expf(-x)));  // g(h_0)
  for (int ch = 0; ch < NCHUNK; ++ch) {
    const int idx = ch * (Bb * Hh) + bh;
    Hinit[idx] = hs;
    hs = fmaf(Pp[idx], hs, Qq[idx]);
  }
}

// ---------------- scan pass 3: in-chunk scan, write outputs ----------------
__global__ void scan_pass3(const unsigned int* __restrict__ P,
                           const float* __restrict__ Hinit,
                           float* __restrict__ out) {
  const int h = blockIdx.x * 256 + threadIdx.x;
  const int ch = blockIdx.y;
  const int b = blockIdx.z;
  float hs = Hinit[ch * (Bb * Hh) + b * Hh + h];
  const size_t base = ((size_t)(b * Tt + ch * CLEN)) * Hh + h;
  const unsigned int* p = P + base;
  float* o = out + base;
#pragma unroll 8
  for (int i = 0; i < CLEN; ++i) {
    const unsigned u = p[(size_t)i * Hh];
    hs = fmaf(bflo(u), hs, bfhi(u));
    o[(size_t)i * Hh] = hs;
  }
}

extern "C" void kernel_launch(void* const* d_in, const int* in_sizes, int n_in,
                              void* d_out, int out_size, void* d_ws, size_t ws_size,
                              hipStream_t stream) {
  const float* x  = (const float*)d_in[0];
  const float* h0 = (const float*)d_in[1];
  const float* Wz = (const float*)d_in[2];
  const float* bz = (const float*)d_in[3];
  const float* Wh = (const float*)d_in[4];
  const float* bh = (const float*)d_in[5];
  float* out = (float*)d_out;

  char* ws = (char*)d_ws;
  unsigned short* xb  = (unsigned short*)(ws);                       // 64 MiB
  unsigned short* wzb = (unsigned short*)(ws + 67108864);            // 2 MiB
  unsigned short* whb = (unsigned short*)(ws + 69206016);            // 2 MiB
  unsigned int*   P   = (unsigned int*)(ws + 71303168);              // 128 MiB
  float* Pp    = (float*)(ws + 205520896);                           // 1 MiB
  float* Qq    = (float*)(ws + 206569472);                           // 1 MiB
  float* Hinit = (float*)(ws + 207618048);                           // 1 MiB

  cvt_kernel<<<4096, 256, 0, stream>>>(x, xb, Mm * Dd / 4);
  cvt_kernel<<<1024, 256, 0, stream>>>(Wz, wzb, Hh * Dd / 4);
  cvt_kernel<<<1024, 256, 0, stream>>>(Wh, whb, Hh * Dd / 4);

  gemm_kernel<<<1024, 512, 0, stream>>>(xb, wzb, whb, bz, bh, P);

  dim3 sgrid(Hh / 256, NCHUNK, Bb);
  scan_pass1<<<sgrid, 256, 0, stream>>>(P, Pp, Qq);
  scan_pass2<<<Bb * Hh / 256, 256, 0, stream>>>(h0, Pp, Qq, Hinit);
  scan_pass3<<<sgrid, 256, 0, stream>>>(P, Hinit, out);
}